// Round 7
// baseline (110.225 us; speedup 1.0000x reference)
//
#include <hip/hip_runtime.h>
#include <hip/hip_bf16.h>
#include <hip/hip_fp8.h>
#include <math.h>

typedef float floatx4 __attribute__((ext_vector_type(4)));
typedef long long i64;
typedef long long i64x2 __attribute__((ext_vector_type(2)));

#define N_ROWS 4096
#define DIM 512
#define LAM 0.5f
#define NT 64                      // 128-row block-tiles per dim (8192/128)
#define NTILES (NT * (NT + 1) / 2) // 2080 triangular tiles

__device__ __forceinline__ unsigned int pack4_fp8(float a, float b, float c, float d) {
    unsigned int u0 = __hip_cvt_float_to_fp8(a, __HIP_SATFINITE, __HIP_E4M3);
    unsigned int u1 = __hip_cvt_float_to_fp8(b, __HIP_SATFINITE, __HIP_E4M3);
    unsigned int u2 = __hip_cvt_float_to_fp8(c, __HIP_SATFINITE, __HIP_E4M3);
    unsigned int u3 = __hip_cvt_float_to_fp8(d, __HIP_SATFINITE, __HIP_E4M3);
    return u0 | (u1 << 8) | (u2 << 16) | (u3 << 24);
}

// One wave per row: L2-normalize 512 fp32 -> fp8 e4m3, stored K-PERMUTED and
// BANK-SWIZZLED. 16-B chunk ch = kt*4+q (kt: 64-k group, q: MFMA quad) holds
// k = kt*64 + {q*8..q*8+7 (lo 8B), 32+q*8..+7 (hi 8B)}; chunk is stored at
// physical position p = ch ^ (row & 7). (The XOR was originally for LDS
// banks; it is harmless for direct-L2 fragment reads - for fixed g,swz the
// four q-chunks remain one contiguous 64-B segment per row.)
__global__ __launch_bounds__(256) void normalize_kernel(
    const float* __restrict__ ei, const float* __restrict__ ej,
    unsigned char* __restrict__ Z, float* __restrict__ out) {
    if (blockIdx.x == 0 && threadIdx.x == 0) out[0] = 0.0f;
    const int w = threadIdx.x >> 6, lane = threadIdx.x & 63;
    const int row = blockIdx.x * 4 + w;                     // [0, 8192)
    const float* __restrict__ src = (row < N_ROWS)
        ? (ei + (size_t)row * DIM)
        : (ej + (size_t)(row - N_ROWS) * DIM);
    const float4* src4 = (const float4*)src;
    float4 v0 = src4[lane];
    float4 v1 = src4[lane + 64];
    float s = v0.x*v0.x + v0.y*v0.y + v0.z*v0.z + v0.w*v0.w
            + v1.x*v1.x + v1.y*v1.y + v1.z*v1.z + v1.w*v1.w;
    #pragma unroll
    for (int off = 32; off; off >>= 1) s += __shfl_xor(s, off);
    const float r = rsqrtf(s);

    __shared__ __align__(16) unsigned char buf[4][512];     // k-linear fp8 rows
    ((unsigned int*)buf[w])[lane]      = pack4_fp8(v0.x*r, v0.y*r, v0.z*r, v0.w*r);
    ((unsigned int*)buf[w])[lane + 64] = pack4_fp8(v1.x*r, v1.y*r, v1.z*r, v1.w*r);
    __syncthreads();

    // full-wave permuted store: lane = kt*8 + q*2 + h, 8 B each
    const int kt = lane >> 3, q = (lane >> 1) & 3, h = lane & 1;
    i64 val = *(const i64*)(buf[w] + kt * 64 + h * 32 + q * 8);
    const int p = (kt * 4 + q) ^ (row & 7);                 // chunk swizzle
    *(i64*)(Z + (size_t)row * DIM + p * 16 + h * 8) = val;
}

// Fused S = Z.Z^T (fp8 16x16x32 MFMA) + loss reduction.
// NEW this round (R6 post-mortem: doubling waves/SIMD was EXACTLY flat, R5
// single-domain was worse, all scheduling micro-fixes flat -> the ~41us
// plateau IS the per-stage barrier-staged structure, not a hiding problem):
//   STRUCTURAL: NO LDS, NO barriers, NO staging. Z (4 MB) is L2-resident
//   (FETCH ~= 8 XCD x 4 MB compulsory). LDS was a pure byte-relay of Z, so
//   each wave now reads its MFMA fragments DIRECTLY from L2 with
//   global_load_dwordx4: addr = base + i*16*DIM + (g>>1)*128 + cOff(g,q,swz)
//   - byte-identical to what the LDS path delivered. Each wave is a fully
//   independent depth-2-prefetch load->MFMA pipeline (register double-buffer
//   afE/afO, statically indexed, full unroll). Total fragment traffic
//   2080*4*64KB ~= 540 MB @ L2 ~34.5 TB/s ~= 16 us, at the 17 us MFMA floor.
//   Per-wave pattern per load: 16 rows x one contiguous 64-B segment.
//   Persistence dropped (nothing to keep warm): plain grid = NTILES, 4-wave
//   blocks of 64x64 sub-tiles, scheduler self-balances 8.125 blocks/CU.
__global__ __launch_bounds__(256, 2) void simloss_kernel(
    const unsigned char* __restrict__ Z, float* __restrict__ out) {
    // --- triangular decode ---
    const int id = blockIdx.x;
    int bm = (int)((2*NT + 1 - sqrtf((float)((2*NT+1)*(2*NT+1)) - 8.0f * (float)id)) * 0.5f);
    if (bm < 0) bm = 0; if (bm > NT-1) bm = NT-1;
    while ((bm + 1) * NT - ((bm + 1) * bm) / 2 <= id) ++bm;
    while (bm * NT - (bm * (bm - 1)) / 2 > id) --bm;
    const int bn = bm + (id - (bm * NT - (bm * (bm - 1)) / 2));

    const int tid = threadIdx.x;
    const int w = tid >> 6, lane = tid & 63;
    const int q = lane >> 4, m16 = lane & 15;
    const int wm = w & 1, wn = w >> 1;
    const int tm = bm * 2 + wm, tn = bn * 2 + wn;   // 64-row tile ids [0,128)

    __shared__ float red[4];

    const int fragSwz = m16 & 7;
    // per-lane fragment bases (row = panel + frag-row + m16)
    const unsigned char* aBase = Z + (size_t)(bm * 128 + wm * 64 + m16) * DIM;
    const unsigned char* bBase = Z + (size_t)(bn * 128 + wn * 64 + m16) * DIM;
    // chunk byte offset within the 128-B k-group region:
    // even g: (q ^ swz)*16 ; odd g: ((4+q) ^ swz)*16 = even ^ 64
    const int cOff0 = (q ^ fragSwz) << 4;
    const int cOff1 = ((4 + q) ^ fragSwz) << 4;

    floatx4 acc[4][4] = {};
    i64x2 afE[4], bfE[4], afO[4], bfO[4];   // register double-buffer

    // load the 8 fragments of one K=64 group (16 B/lane each, direct L2)
    #define LOADG(af, bf, koff, co)                                              \
        _Pragma("unroll")                                                        \
        for (int i = 0; i < 4; ++i)                                              \
            af[i] = *(const i64x2*)(aBase + (size_t)i * 16 * DIM + (koff) + (co)); \
        _Pragma("unroll")                                                        \
        for (int j = 0; j < 4; ++j)                                              \
            bf[j] = *(const i64x2*)(bBase + (size_t)j * 16 * DIM + (koff) + (co));

    // consume one group: x-pass (16 independent) then y-pass (dep dist 16)
    #define CONSUME(af, bf)                                                      \
        _Pragma("unroll")                                                        \
        for (int i = 0; i < 4; ++i)                                              \
            _Pragma("unroll")                                                    \
            for (int j = 0; j < 4; ++j)                                          \
                acc[i][j] = __builtin_amdgcn_mfma_f32_16x16x32_fp8_fp8(af[i].x, bf[j].x, acc[i][j], 0, 0, 0); \
        _Pragma("unroll")                                                        \
        for (int i = 0; i < 4; ++i)                                              \
            _Pragma("unroll")                                                    \
            for (int j = 0; j < 4; ++j)                                          \
                acc[i][j] = __builtin_amdgcn_mfma_f32_16x16x32_fp8_fp8(af[i].y, bf[j].y, acc[i][j], 0, 0, 0);

    // 8 K=64 groups, depth-2 register prefetch, fully static indexing
    LOADG(afE, bfE, 0, cOff0)
    #pragma unroll
    for (int h = 0; h < 4; ++h) {
        LOADG(afO, bfO, h * 128, cOff1)          // prefetch odd g=2h+1
        CONSUME(afE, bfE)                        // consume even g=2h
        if (h < 3) { LOADG(afE, bfE, (h + 1) * 128, cOff0) }  // prefetch g=2h+2
        CONSUME(afO, bfO)                        // consume odd g=2h+1
    }

    // --- epilogue: C/D map row = i*16 + q*4 + r, col = j*16 + m16 (tile-local) ---
    const float wgt = (tn < tm) ? 0.0f : ((tm == tn) ? 1.0f : 2.0f);
    const bool hasPos = (tn == tm + 64);           // wave-uniform
    float negsum = 0.0f, possum = 0.0f;
    if (wgt != 0.0f) {
        const int rowBase = tm * 64 + q * 4;
        const int colBase = tn * 64 + m16;
        #pragma unroll
        for (int j = 0; j < 4; ++j) {
            const int cg = colBase + j * 16;
            float p = 1.0f;
            #pragma unroll
            for (int i = 0; i < 4; ++i) {
                const int rg0 = rowBase + i * 16;
                #pragma unroll
                for (int r = 0; r < 4; ++r) {
                    const float sv = acc[i][j][r];
                    float e = __expf(sv - LAM);
                    if (rg0 + r == cg) e = 0.0f;          // mask main diagonal
                    p *= (1.0f + e);
                    if (hasPos && cg == rg0 + r + N_ROWS) // positive pair
                        possum += log1pf(expf(-sv + LAM));
                }
            }
            negsum += __logf(p);
        }
        negsum *= wgt;
    }

    #pragma unroll
    for (int off = 32; off; off >>= 1) {
        negsum += __shfl_xor(negsum, off);
        possum += __shfl_xor(possum, off);
    }
    const float part = negsum * (1.0f / (12.0f * (float)N_ROWS))
                     + possum * (1.0f / (float)N_ROWS);
    if (lane == 0) red[w] = part;
    __syncthreads();
    if (tid == 0) atomicAdd(out, red[0] + red[1] + red[2] + red[3]);
    #undef LOADG
    #undef CONSUME
}

extern "C" void kernel_launch(void* const* d_in, const int* in_sizes, int n_in,
                              void* d_out, int out_size, void* d_ws, size_t ws_size,
                              hipStream_t stream) {
    const float* ei = (const float*)d_in[0];
    const float* ej = (const float*)d_in[1];
    float* out = (float*)d_out;
    unsigned char* Z = (unsigned char*)d_ws;  // 8192*512 fp8 = 4 MB scratch

    normalize_kernel<<<2048, 256, 0, stream>>>(ei, ej, Z, out);
    simloss_kernel<<<NTILES, 256, 0, stream>>>(Z, out);
}